// Round 1
// baseline (70.337 us; speedup 1.0000x reference)
//
#include <hip/hip_runtime.h>
#include <math.h>

// Problem constants (match setup_inputs)
#define B_ 4
#define N_ 128
#define D_ 160
#define H_ 192
#define W_ 160

// ---------------------------------------------------------------------------
// Kernel 1: weighted Kabsch rigid transform, one block (128 threads) per batch.
// theta[b] = [R | T] row-major 3x4, written to workspace.
//
// Reference math: p1 = points_f, p2 = points_m, w normalized.
//   c1 = sum w*p1 ; c2 = sum w*p2
//   H[i][j] = sum_n w^2 (p1_i - c1_i)(p2_j - c2_j)
//   SVD H = U S V^T ; R_init = V U^T  (== Q^T, Q = orth. polar factor of H)
//   R = diag(1,1,sign(det(R_init))) * R_init       (ref scales 3rd ROW of V)
//   T = c2 - R c1
// ---------------------------------------------------------------------------
__global__ void rigid_kernel(const float* __restrict__ pm,
                             const float* __restrict__ pf,
                             const float* __restrict__ wt,
                             float* __restrict__ theta) {
  __shared__ float sm[2];
  __shared__ float bc[15]; // c1(3), c2(3), H(9)
  const int b = blockIdx.x;
  const int n = threadIdx.x; // 0..127

  const float w  = wt[b * N_ + n];
  const float f0 = pf[(b * N_ + n) * 3 + 0];
  const float f1 = pf[(b * N_ + n) * 3 + 1];
  const float f2 = pf[(b * N_ + n) * 3 + 2];
  const float m0 = pm[(b * N_ + n) * 3 + 0];
  const float m1 = pm[(b * N_ + n) * 3 + 1];
  const float m2 = pm[(b * N_ + n) * 3 + 2];

  // --- centroids: 6 reductions over 128 lanes (2 waves) ---
  float vals[6] = {w * f0, w * f1, w * f2, w * m0, w * m1, w * m2};
#pragma unroll
  for (int k = 0; k < 6; ++k) {
    float v = vals[k];
#pragma unroll
    for (int o = 32; o > 0; o >>= 1) v += __shfl_down(v, o, 64);
    if ((n & 63) == 0) sm[n >> 6] = v;
    __syncthreads();
    if (n == 0) bc[k] = sm[0] + sm[1];
    __syncthreads();
  }
  const float c10 = bc[0], c11 = bc[1], c12 = bc[2];
  const float c20 = bc[3], c21 = bc[4], c22 = bc[5];

  const float q1[3] = {(f0 - c10) * w, (f1 - c11) * w, (f2 - c12) * w};
  const float q2[3] = {(m0 - c20) * w, (m1 - c21) * w, (m2 - c22) * w};

  // --- cross-covariance: 9 reductions ---
#pragma unroll
  for (int i = 0; i < 3; ++i)
#pragma unroll
    for (int j = 0; j < 3; ++j) {
      float v = q1[i] * q2[j];
#pragma unroll
      for (int o = 32; o > 0; o >>= 1) v += __shfl_down(v, o, 64);
      if ((n & 63) == 0) sm[n >> 6] = v;
      __syncthreads();
      if (n == 0) bc[6 + i * 3 + j] = sm[0] + sm[1];
      __syncthreads();
    }

  if (n == 0) {
    // --- polar decomposition via Newton iteration (f64, scalar) ---
    double X[3][3];
    double fr = 0.0;
    for (int i = 0; i < 3; ++i)
      for (int j = 0; j < 3; ++j) {
        X[i][j] = (double)bc[6 + i * 3 + j];
        fr += X[i][j] * X[i][j];
      }
    fr = sqrt(fr);
    if (fr < 1e-300) fr = 1.0;
    for (int i = 0; i < 3; ++i)
      for (int j = 0; j < 3; ++j) X[i][j] /= fr;

    for (int it = 0; it < 40; ++it) {
      double C[3][3];
      C[0][0] =  X[1][1] * X[2][2] - X[1][2] * X[2][1];
      C[0][1] = -(X[1][0] * X[2][2] - X[1][2] * X[2][0]);
      C[0][2] =  X[1][0] * X[2][1] - X[1][1] * X[2][0];
      C[1][0] = -(X[0][1] * X[2][2] - X[0][2] * X[2][1]);
      C[1][1] =  X[0][0] * X[2][2] - X[0][2] * X[2][0];
      C[1][2] = -(X[0][0] * X[2][1] - X[0][1] * X[2][0]);
      C[2][0] =  X[0][1] * X[1][2] - X[0][2] * X[1][1];
      C[2][1] = -(X[0][0] * X[1][2] - X[0][2] * X[1][0]);
      C[2][2] =  X[0][0] * X[1][1] - X[0][1] * X[1][0];
      double det = X[0][0] * C[0][0] + X[0][1] * C[0][1] + X[0][2] * C[0][2];
      double inv_det = 1.0 / det;
      // X <- 0.5 * (X + inv(X)^T) ; inv(X)^T = C / det
      for (int i = 0; i < 3; ++i)
        for (int j = 0; j < 3; ++j)
          X[i][j] = 0.5 * (X[i][j] + C[i][j] * inv_det);
    }

    // R_init = X^T (= V U^T)
    double R[3][3];
    for (int i = 0; i < 3; ++i)
      for (int j = 0; j < 3; ++j) R[i][j] = X[j][i];

    double det = R[0][0] * (R[1][1] * R[2][2] - R[1][2] * R[2][1])
               - R[0][1] * (R[1][0] * R[2][2] - R[1][2] * R[2][0])
               + R[0][2] * (R[1][0] * R[2][1] - R[1][1] * R[2][0]);
    double s = (det < 0.0) ? -1.0 : 1.0;
    R[2][0] *= s; R[2][1] *= s; R[2][2] *= s;

    const double c1d[3] = {c10, c11, c12};
    const double c2d[3] = {c20, c21, c22};
    for (int i = 0; i < 3; ++i) {
      double Ti = c2d[i] - (R[i][0] * c1d[0] + R[i][1] * c1d[1] + R[i][2] * c1d[2]);
      theta[b * 12 + i * 4 + 0] = (float)R[i][0];
      theta[b * 12 + i * 4 + 1] = (float)R[i][1];
      theta[b * 12 + i * 4 + 2] = (float)R[i][2];
      theta[b * 12 + i * 4 + 3] = (float)Ti;
    }
  }
}

// ---------------------------------------------------------------------------
// Kernel 2: affine grid generation. Write-streaming (236 MB out).
// out[b,d,h,w,i] = theta[b,i,0]*x + theta[b,i,1]*y + theta[b,i,2]*z + theta[b,i,3]
//   x = (2w+1)/W - 1, y = (2h+1)/H - 1, z = (2d+1)/D - 1
// One thread = 4 consecutive voxels (48 B) in one row; 3x float4 stores.
// 4 | W so a chunk never straddles a row.
// ---------------------------------------------------------------------------
__global__ __launch_bounds__(256) void grid_kernel(const float* __restrict__ theta,
                                                   float* __restrict__ out) {
  const int CPR = W_ / 4; // chunks per row = 40
  const int t = blockIdx.x * 256 + threadIdx.x; // chunk id, exact fit

  const int row = t / CPR;
  const int w0 = (t - row * CPR) * 4;
  const int h = row % H_;
  const int rd = row / H_;
  const int d = rd % D_;
  const int b = rd / D_;

  const float y = (2.0f * (float)h + 1.0f) / (float)H_ - 1.0f;
  const float z = (2.0f * (float)d + 1.0f) / (float)D_ - 1.0f;

  const float4* thv = (const float4*)(theta + b * 12);
  const float4 r0 = thv[0]; // R00 R01 R02 T0
  const float4 r1 = thv[1];
  const float4 r2 = thv[2];

  const float C0 = fmaf(r0.y, y, fmaf(r0.z, z, r0.w));
  const float C1 = fmaf(r1.y, y, fmaf(r1.z, z, r1.w));
  const float C2 = fmaf(r2.y, y, fmaf(r2.z, z, r2.w));

  float o[12];
#pragma unroll
  for (int j = 0; j < 4; ++j) {
    const float x = (2.0f * (float)(w0 + j) + 1.0f) / (float)W_ - 1.0f;
    o[j * 3 + 0] = fmaf(r0.x, x, C0);
    o[j * 3 + 1] = fmaf(r1.x, x, C1);
    o[j * 3 + 2] = fmaf(r2.x, x, C2);
  }

  float4* outv = (float4*)(out + (size_t)t * 12);
  outv[0] = make_float4(o[0], o[1], o[2], o[3]);
  outv[1] = make_float4(o[4], o[5], o[6], o[7]);
  outv[2] = make_float4(o[8], o[9], o[10], o[11]);
}

extern "C" void kernel_launch(void* const* d_in, const int* in_sizes, int n_in,
                              void* d_out, int out_size, void* d_ws, size_t ws_size,
                              hipStream_t stream) {
  const float* pm = (const float*)d_in[0]; // points_m [B,N,3]
  const float* pf = (const float*)d_in[1]; // points_f [B,N,3]
  const float* wt = (const float*)d_in[2]; // weights  [B,1,N]
  float* theta = (float*)d_ws;             // [B,3,4]
  float* out = (float*)d_out;              // [B,D,H,W,3] f32

  rigid_kernel<<<B_, N_, 0, stream>>>(pm, pf, wt, theta);

  const int nChunks = B_ * D_ * H_ * (W_ / 4); // 4,915,200 = 19200 * 256
  grid_kernel<<<nChunks / 256, 256, 0, stream>>>(theta, out);
}

// Round 2
// 50.117 us; speedup vs baseline: 1.4035x; 1.4035x over previous
//
#include <hip/hip_runtime.h>
#include <math.h>

// Problem constants (match setup_inputs)
#define B_ 4
#define N_ 128
#define D_ 160
#define H_ 192
#define W_ 160

// ---------------------------------------------------------------------------
// Kernel 1: weighted Kabsch rigid transform.
// ONE block, 256 threads: wave b (of 4) handles batch b, each lane 2 points.
// All reductions are wave-local __shfl_xor butterflies (no barriers).
// Polar decomposition: det-scaled Newton X <- 0.5*(mu*X + C/(mu*det)),
// 12 iters in f64, run SIMD-parallel on lanes 0..3 (one per batch).
//
// Reference math: p1 = points_f, p2 = points_m, w normalized.
//   c1 = sum w*p1 ; c2 = sum w*p2
//   H[i][j] = sum_n w^2 (p1_i - c1_i)(p2_j - c2_j)
//   R_init = V U^T = Q^T (Q = orthogonal polar factor of H)
//   R = diag(1,1,sign(det(R_init))) * R_init   (ref scales 3rd ROW of V)
//   T = c2 - R c1
// ---------------------------------------------------------------------------
__global__ __launch_bounds__(256) void rigid_kernel(const float* __restrict__ pm,
                                                    const float* __restrict__ pf,
                                                    const float* __restrict__ wt,
                                                    float* __restrict__ theta) {
  __shared__ float bc[B_][15]; // per batch: c1(3), c2(3), H(9)
  const int tid = threadIdx.x;
  const int b = tid >> 6;     // wave index = batch
  const int lane = tid & 63;

  // two points per lane: n = lane, lane+64
  const int base = b * N_;
  float wA = wt[base + lane], wB = wt[base + lane + 64];
  float fA[3], fB[3], mA[3], mB[3];
#pragma unroll
  for (int c = 0; c < 3; ++c) {
    fA[c] = pf[(base + lane) * 3 + c];
    fB[c] = pf[(base + lane + 64) * 3 + c];
    mA[c] = pm[(base + lane) * 3 + c];
    mB[c] = pm[(base + lane + 64) * 3 + c];
  }

  // --- centroids: 6 wave butterfly reductions (pipelined, no barriers) ---
  float sums[6];
#pragma unroll
  for (int c = 0; c < 3; ++c) {
    sums[c]     = wA * fA[c] + wB * fB[c];
    sums[3 + c] = wA * mA[c] + wB * mB[c];
  }
#pragma unroll
  for (int k = 0; k < 6; ++k) {
    float v = sums[k];
#pragma unroll
    for (int o = 1; o < 64; o <<= 1) v += __shfl_xor(v, o, 64);
    sums[k] = v;
  }

  // --- cross-covariance H: 9 butterfly reductions ---
  float q1A[3], q1B[3], q2A[3], q2B[3];
#pragma unroll
  for (int c = 0; c < 3; ++c) {
    q1A[c] = (fA[c] - sums[c]) * wA;     q1B[c] = (fB[c] - sums[c]) * wB;
    q2A[c] = (mA[c] - sums[3 + c]) * wA; q2B[c] = (mB[c] - sums[3 + c]) * wB;
  }
  float Hm[9];
#pragma unroll
  for (int i = 0; i < 3; ++i)
#pragma unroll
    for (int j = 0; j < 3; ++j)
      Hm[i * 3 + j] = q1A[i] * q2A[j] + q1B[i] * q2B[j];
#pragma unroll
  for (int k = 0; k < 9; ++k) {
    float v = Hm[k];
#pragma unroll
    for (int o = 1; o < 64; o <<= 1) v += __shfl_xor(v, o, 64);
    Hm[k] = v;
  }

  if (lane == 0) {
#pragma unroll
    for (int k = 0; k < 6; ++k) bc[b][k] = sums[k];
#pragma unroll
    for (int k = 0; k < 9; ++k) bc[b][6 + k] = Hm[k];
  }
  __syncthreads();

  // --- polar solve: lanes 0..3 of wave 0, SIMD-parallel over batches ---
  if (tid < B_) {
    const int bb = tid;
    double X[3][3];
    double fr = 0.0;
    for (int i = 0; i < 3; ++i)
      for (int j = 0; j < 3; ++j) {
        X[i][j] = (double)bc[bb][6 + i * 3 + j];
        fr += X[i][j] * X[i][j];
      }
    fr = sqrt(fr);
    if (fr < 1e-300) fr = 1.0;
    for (int i = 0; i < 3; ++i)
      for (int j = 0; j < 3; ++j) X[i][j] /= fr;

    for (int it = 0; it < 12; ++it) {
      double C[3][3];
      C[0][0] =  X[1][1] * X[2][2] - X[1][2] * X[2][1];
      C[0][1] = -(X[1][0] * X[2][2] - X[1][2] * X[2][0]);
      C[0][2] =  X[1][0] * X[2][1] - X[1][1] * X[2][0];
      C[1][0] = -(X[0][1] * X[2][2] - X[0][2] * X[2][1]);
      C[1][1] =  X[0][0] * X[2][2] - X[0][2] * X[2][0];
      C[1][2] = -(X[0][0] * X[2][1] - X[0][1] * X[2][0]);
      C[2][0] =  X[0][1] * X[1][2] - X[0][2] * X[1][1];
      C[2][1] = -(X[0][0] * X[1][2] - X[0][2] * X[1][0]);
      C[2][2] =  X[0][0] * X[1][1] - X[0][1] * X[1][0];
      double det = X[0][0] * C[0][0] + X[0][1] * C[0][1] + X[0][2] * C[0][2];
      double ad = fabs(det);
      // accelerated Newton: mu = |det|^(-1/3)
      double mu = (ad > 1e-300 && ad < 1e300) ? pow(ad, -1.0 / 3.0) : 1.0;
      double inv = 1.0 / (mu * det);
      for (int i = 0; i < 3; ++i)
        for (int j = 0; j < 3; ++j)
          X[i][j] = 0.5 * (mu * X[i][j] + C[i][j] * inv);
    }

    // R_init = X^T (= V U^T)
    double R[3][3];
    for (int i = 0; i < 3; ++i)
      for (int j = 0; j < 3; ++j) R[i][j] = X[j][i];

    double det = R[0][0] * (R[1][1] * R[2][2] - R[1][2] * R[2][1])
               - R[0][1] * (R[1][0] * R[2][2] - R[1][2] * R[2][0])
               + R[0][2] * (R[1][0] * R[2][1] - R[1][1] * R[2][0]);
    double s = (det < 0.0) ? -1.0 : 1.0;
    R[2][0] *= s; R[2][1] *= s; R[2][2] *= s;

    const double c1d[3] = {bc[bb][0], bc[bb][1], bc[bb][2]};
    const double c2d[3] = {bc[bb][3], bc[bb][4], bc[bb][5]};
    for (int i = 0; i < 3; ++i) {
      double Ti = c2d[i] - (R[i][0] * c1d[0] + R[i][1] * c1d[1] + R[i][2] * c1d[2]);
      theta[bb * 12 + i * 4 + 0] = (float)R[i][0];
      theta[bb * 12 + i * 4 + 1] = (float)R[i][1];
      theta[bb * 12 + i * 4 + 2] = (float)R[i][2];
      theta[bb * 12 + i * 4 + 3] = (float)Ti;
    }
  }
}

// ---------------------------------------------------------------------------
// Kernel 2: affine grid generation. Write-streaming (236 MB out).
// out[b,d,h,w,i] = theta[b,i,0]*x + theta[b,i,1]*y + theta[b,i,2]*z + theta[b,i,3]
//   x = (2w+1)/W - 1, y = (2h+1)/H - 1, z = (2d+1)/D - 1
// One thread = ONE output float4 -> every store instruction is 1 KiB of
// fully-contiguous bytes per wave (perfect coalescing). A float4 (4 floats)
// spans 2 adjacent voxels of one row (480 floats/row, 4 | 480); phase = f%3
// selects the 4 needed components from {A0,A1,A2,B0,B1,B2}.
// ---------------------------------------------------------------------------
__global__ __launch_bounds__(256) void grid_kernel(const float* __restrict__ theta,
                                                   float4* __restrict__ out) {
  const int F_PER_ROW = (W_ * 3) / 4; // 120 float4s per row
  const int f = blockIdx.x * 256 + threadIdx.x; // float4 index, exact fit

  const int row = f / F_PER_ROW;
  const int lf4 = f - row * F_PER_ROW;
  const int h = row % H_;
  const int rd = row / H_;
  const int d = rd % D_;
  const int b = rd / D_;

  const int lf = lf4 * 4;        // float offset within row, 0..476
  const int w0 = lf / 3;         // first voxel covered
  const int phase = lf - 3 * w0; // 0,1,2

  const float y = (2.0f * (float)h + 1.0f) * (1.0f / (float)H_) - 1.0f;
  const float z = (2.0f * (float)d + 1.0f) * (1.0f / (float)D_) - 1.0f;
  const float x0 = (2.0f * (float)w0 + 1.0f) * (1.0f / (float)W_) - 1.0f;

  const float4* thv = (const float4*)(theta + b * 12);
  const float4 r0 = thv[0]; // R00 R01 R02 T0
  const float4 r1 = thv[1];
  const float4 r2 = thv[2];

  const float A0 = fmaf(r0.x, x0, fmaf(r0.y, y, fmaf(r0.z, z, r0.w)));
  const float A1 = fmaf(r1.x, x0, fmaf(r1.y, y, fmaf(r1.z, z, r1.w)));
  const float A2 = fmaf(r2.x, x0, fmaf(r2.y, y, fmaf(r2.z, z, r2.w)));
  const float dx = 2.0f / (float)W_;
  const float B0 = fmaf(r0.x, dx, A0);
  const float B1 = fmaf(r1.x, dx, A1);
  const float B2 = fmaf(r2.x, dx, A2);

  float4 o;
  o.x = (phase == 0) ? A0 : ((phase == 1) ? A1 : A2);
  o.y = (phase == 0) ? A1 : ((phase == 1) ? A2 : B0);
  o.z = (phase == 0) ? A2 : ((phase == 1) ? B0 : B1);
  o.w = (phase == 0) ? B0 : ((phase == 1) ? B1 : B2);

  out[f] = o;
}

extern "C" void kernel_launch(void* const* d_in, const int* in_sizes, int n_in,
                              void* d_out, int out_size, void* d_ws, size_t ws_size,
                              hipStream_t stream) {
  const float* pm = (const float*)d_in[0]; // points_m [B,N,3]
  const float* pf = (const float*)d_in[1]; // points_f [B,N,3]
  const float* wt = (const float*)d_in[2]; // weights  [B,1,N]
  float* theta = (float*)d_ws;             // [B,3,4]
  float4* out = (float4*)d_out;            // [B,D,H,W,3] f32 as float4s

  rigid_kernel<<<1, 256, 0, stream>>>(pm, pf, wt, theta);

  const int nF4 = B_ * D_ * H_ * W_ * 3 / 4; // 14,745,600 = 57600 * 256
  grid_kernel<<<nF4 / 256, 256, 0, stream>>>(theta, out);
}